// Round 18
// baseline (183.353 us; speedup 1.0000x reference)
//
#include <hip/hip_runtime.h>
#include <hip/hip_fp16.h>
#include <math.h>

#define NNODES 40000
#define NEDGES 640000
#define HC 128     // heads*channels
#define OUTC 32
#define NBLK   ((NNODES + 255) / 256)   // 157 scan blocks

typedef __attribute__((ext_vector_type(8))) _Float16 v8h;
typedef __attribute__((ext_vector_type(2))) _Float16 v2h;
typedef __attribute__((ext_vector_type(4))) float    v4f;

__device__ __forceinline__ v2h h2bits(unsigned u)
{
    union { unsigned u; v2h h; } c; c.u = u; return c.h;
}
__device__ __forceinline__ float h2f(unsigned short u)
{
    return __half2float(__ushort_as_half(u));
}
__device__ __forceinline__ unsigned hbits(float f)
{
    return (unsigned)__half_as_ushort(__float2half(f));
}

// ---------------------------------------------------------------------------
// Phase 0 (FUSED): blocks [0, CB) do per-dst counts + slot record;
// blocks [CB, ...) convert x / W matrices to fp16.
// ---------------------------------------------------------------------------
#define CB ((NEDGES + 255) / 256)                    // 2500 count blocks
#define SX4 (NNODES * 64 / 4)                        // float4 groups of x
#define CONV (SX4 + 2 * 128 * 64 + 2 * 128 * 128)    // convert elements

__global__ void count_convert_kernel(const int* __restrict__ dst, int* __restrict__ cnt,
                                     int* __restrict__ slot,
                                     const float* __restrict__ x,
                                     const float* __restrict__ Wl1, const float* __restrict__ Wr1,
                                     const float* __restrict__ Wl2, const float* __restrict__ Wr2,
                                     __half* __restrict__ x16,
                                     __half* __restrict__ WH1, __half* __restrict__ WH2)
{
    int b = blockIdx.x;
    if (b < CB) {
        int e = b * 256 + threadIdx.x;
        if (e >= NEDGES) return;
        slot[e] = atomicAdd(&cnt[dst[e]], 1);
        return;
    }
    int i = (b - CB) * 256 + threadIdx.x;
    if (i < SX4) {
        float4 v = ((const float4*)x)[i];
        __half tmp[4] = {__float2half(v.x), __float2half(v.y),
                         __float2half(v.z), __float2half(v.w)};
        ((uint2*)x16)[i] = *(const uint2*)tmp;
        return;
    }
    int j = i - SX4;
    if (j < 128 * 64)            { WH1[j] = __float2half(Wl1[j]); return; }
    j -= 128 * 64;
    if (j < 128 * 64)            { WH1[128 * 64 + j] = __float2half(Wr1[j]); return; }
    j -= 128 * 64;
    if (j < 128 * 128)           { WH2[j] = __float2half(Wl2[j]); return; }
    j -= 128 * 128;
    if (j < 128 * 128)           { WH2[128 * 128 + j] = __float2half(Wr2[j]); return; }
}

// ---------------------------------------------------------------------------
// Two-level exclusive scan of cnt[n] (real edges only; self loops are
// handled inline in agg now) over 40000 nodes.
// ---------------------------------------------------------------------------
__global__ __launch_bounds__(256) void scan1_kernel(const int* __restrict__ cnt,
                                                    int* __restrict__ offsets,
                                                    int* __restrict__ blocksum)
{
    __shared__ int s[256];
    int t = threadIdx.x;
    int n = blockIdx.x * 256 + t;
    int v = (n < NNODES) ? cnt[n] : 0;
    s[t] = v;
    __syncthreads();
    for (int off = 1; off < 256; off <<= 1) {
        int u = (t >= off) ? s[t - off] : 0;
        __syncthreads();
        s[t] += u;
        __syncthreads();
    }
    if (n < NNODES) offsets[n] = s[t] - v;     // exclusive local prefix
    if (t == 255) blocksum[blockIdx.x] = s[255];
}

__global__ __launch_bounds__(256) void scan2_kernel(int* __restrict__ blocksum)
{
    __shared__ int s[256];
    int t = threadIdx.x;
    int v = (t < NBLK) ? blocksum[t] : 0;
    s[t] = v;
    __syncthreads();
    for (int off = 1; off < 256; off <<= 1) {
        int u = (t >= off) ? s[t - off] : 0;
        __syncthreads();
        s[t] += u;
        __syncthreads();
    }
    if (t < NBLK) blocksum[t] = s[t] - v;      // exclusive
}

__global__ __launch_bounds__(256) void scan3_kernel(int* __restrict__ offsets,
                                                    const int* __restrict__ blocksum)
{
    int n = blockIdx.x * 256 + threadIdx.x;
    if (n >= NNODES) return;
    offsets[n] += blocksum[blockIdx.x];
    if (n == 0) offsets[NNODES] = NEDGES;
}

// ---------------------------------------------------------------------------
// MFMA node transform body: D[chan][node] = W(fp16)[chan][k] . X(fp16)[node][k]
// ---------------------------------------------------------------------------
template <int K>
__device__ __forceinline__ void transform_body(
    int bx, int t,
    const __half* __restrict__ X16, const __half* __restrict__ WH,
    const float* __restrict__ bl, const float* __restrict__ br,
    __half* __restrict__ XLo, __half* __restrict__ XRo)
{
    int w = t >> 6, lane = t & 63;
    int nb = bx * 32;
    int mb = w * 64;                 // channel base of this wave (0..192)
    int l15 = lane & 15, lg = lane >> 4;

    v4f acc[4][2];
#pragma unroll
    for (int mt = 0; mt < 4; mt++)
#pragma unroll
        for (int nt = 0; nt < 2; nt++) acc[mt][nt] = (v4f){0.f, 0.f, 0.f, 0.f};

#pragma unroll
    for (int kb = 0; kb < K; kb += 32) {
        int kf = kb + lg * 8;
        v8h bfr[2], afr[4];
#pragma unroll
        for (int nt = 0; nt < 2; nt++)
            bfr[nt] = *(const v8h*)&X16[(size_t)(nb + nt * 16 + l15) * K + kf];
#pragma unroll
        for (int mt = 0; mt < 4; mt++)
            afr[mt] = *(const v8h*)&WH[(size_t)(mb + mt * 16 + l15) * K + kf];
#pragma unroll
        for (int mt = 0; mt < 4; mt++)
#pragma unroll
            for (int nt = 0; nt < 2; nt++)
                acc[mt][nt] = __builtin_amdgcn_mfma_f32_16x16x32_f16(
                    afr[mt], bfr[nt], acc[mt][nt], 0, 0, 0);
    }

    bool isR = mb >= 128;                  // wave-uniform
    const float* bias = isR ? br : bl;
    __half* Out       = isR ? XRo : XLo;
    int cb = (mb & 127);
#pragma unroll
    for (int mt = 0; mt < 4; mt++) {
        int cc = cb + mt * 16 + lg * 4;    // 4 consecutive channels
        float b0 = bias[cc], b1 = bias[cc + 1], b2 = bias[cc + 2], b3 = bias[cc + 3];
#pragma unroll
        for (int nt = 0; nt < 2; nt++) {
            int n = nb + nt * 16 + l15;
            __half tmp[4] = {__float2half(acc[mt][nt][0] + b0),
                             __float2half(acc[mt][nt][1] + b1),
                             __float2half(acc[mt][nt][2] + b2),
                             __float2half(acc[mt][nt][3] + b3)};
            *(uint2*)&Out[(size_t)n * HC + cc] = *(const uint2*)tmp;
        }
    }
}

template <int K>
__global__ __launch_bounds__(256) void transform_mfma_kernel(
    const __half* __restrict__ X16, const __half* __restrict__ WH,
    const float* __restrict__ bl, const float* __restrict__ br,
    __half* __restrict__ XLo, __half* __restrict__ XRo)
{
    transform_body<K>(blockIdx.x, threadIdx.x, X16, WH, bl, br, XLo, XRo);
}

// ---------------------------------------------------------------------------
// Phase 2 (FUSED with layer-1 transform): blocks [0, CB) place real edges
// ATOMIC-FREE into CSR-by-dst as 8-byte uint2 records
//   {src | e0f16<<16,  e1f16 | e2f16<<16}
// Blocks [CB, CB+1250) run the K=64 MFMA transform.
// ---------------------------------------------------------------------------
__global__ __launch_bounds__(256) void place_transform_kernel(
    const int* __restrict__ src, const int* __restrict__ dst,
    const float* __restrict__ eattr,
    const int* __restrict__ offsets, const int* __restrict__ slot,
    uint2* __restrict__ csr2,
    const __half* __restrict__ X16, const __half* __restrict__ WH,
    const float* __restrict__ bl, const float* __restrict__ br,
    __half* __restrict__ XLo, __half* __restrict__ XRo)
{
    int b = blockIdx.x;
    if (b < CB) {
        int e = b * 256 + threadIdx.x;
        if (e >= NEDGES) return;
        int d = dst[e];
        int pos = offsets[d] + slot[e];
        uint2 rec;
        rec.x = (unsigned)src[e] | (hbits(eattr[e * 3 + 0]) << 16);
        rec.y = hbits(eattr[e * 3 + 1]) | (hbits(eattr[e * 3 + 2]) << 16);
        csr2[pos] = rec;
        return;
    }
    transform_body<64>(b - CB, threadIdx.x, X16, WH, bl, br, XLo, XRo);
}

// ---------------------------------------------------------------------------
// Cross-lane helpers, all DPP (VALU pipe, no lgkm wait).
// ---------------------------------------------------------------------------
template <int CTRL>
__device__ __forceinline__ float dpp_swap(float x)
{
    return __int_as_float(__builtin_amdgcn_update_dpp(
        0, __float_as_int(x), CTRL, 0xF, 0xF, true));
}

// ---------------------------------------------------------------------------
// GATv2 attention + aggregation, one wave per node, 8 independent
// accumulator states, packed-fp16 logits, no-max exp2 softmax, f32 accum.
// SELF-LOOP FOLDED IN: while scanning real edges, the wave accumulates the
// three attr sums in f32 (hidden in gather-stall slots); the self-loop is
// processed as one final EDGE_STEP with xl = XL[n] and mean attrs
// (PyG add_self_loops fill_value='mean'). No loopattr kernel, no self
// records in the CSR.
// ---------------------------------------------------------------------------
template <int FUSE>
__global__ __launch_bounds__(256) void agg_kernel(
    const __half* __restrict__ XL, const __half* __restrict__ XR,
    const uint2* __restrict__ csr2, const int* __restrict__ offsets,
    const float* __restrict__ We, const float* __restrict__ att,
    const float* __restrict__ bias, __half* __restrict__ OUT,
    const float* __restrict__ Wf, const float* __restrict__ bf,
    float* __restrict__ out2)
{
    __shared__ float wf_s[FUSE ? OUTC * 132 : 1];   // pad 132 keeps rows 16B-aligned
    __shared__ float hrow[FUSE ? 4 * HC : 1];

    int t = threadIdx.x;
    if (FUSE) {
        for (int i = t * 4; i < OUTC * HC; i += 1024) {       // float4 staging
            float4 v = *(const float4*)&Wf[i];
            *(float4*)&wf_s[(i >> 7) * 132 + (i & 127)] = v;
        }
        __syncthreads();   // at kernel start: zero skew
    }

    int w = t >> 6;
    int n = __builtin_amdgcn_readfirstlane(blockIdx.x * 4 + w);
    int lane = t & 63;
    int c0 = lane * 2;

    const float LOG2E = 1.44269504088896340736f;
    v2h xr2 = *(const v2h*)&XR[(size_t)n * HC + c0];
    float2 atf = *(const float2*)&att[c0];
    v2h at2 = {(_Float16)(atf.x * LOG2E), (_Float16)(atf.y * LOG2E)};
    v2h we0 = {(_Float16)We[c0 * 3 + 0], (_Float16)We[c0 * 3 + 3]};
    v2h we1 = {(_Float16)We[c0 * 3 + 1], (_Float16)We[c0 * 3 + 4]};
    v2h we2 = {(_Float16)We[c0 * 3 + 2], (_Float16)We[c0 * 3 + 5]};
    const v2h vk02 = {(_Float16)0.2f, (_Float16)0.2f};

    int beg = offsets[n], end = offsets[n + 1];

    float dacc[8], a0[8], a1[8];
#pragma unroll
    for (int i = 0; i < 8; i++) { dacc[i] = 0.f; a0[i] = 0.f; a1[i] = 0.f; }
    float as0 = 0.f, as1 = 0.f, as2 = 0.f;     // self-loop attr sums (f32)

#define DECODE(q, s_, e00_, e11_, e22_)                                        \
    {                                                                          \
        unsigned qx = (unsigned)__builtin_amdgcn_readfirstlane((int)q.x);      \
        unsigned qy = (unsigned)__builtin_amdgcn_readfirstlane((int)q.y);      \
        s_   = (int)(qx & 0xffffu);                                            \
        e00_ = (qx >> 16) * 0x10001u;                                          \
        e11_ = (qy & 0xffffu) * 0x10001u;                                      \
        e22_ = (qy & 0xffff0000u) | (qy >> 16);                                \
        as0 += h2f((unsigned short)(qx >> 16));                                \
        as1 += h2f((unsigned short)(qy & 0xffffu));                            \
        as2 += h2f((unsigned short)(qy >> 16));                                \
    }

#define EDGE_STEP(e00, e11, e22, xl2, d_, a0_, a1_)                            \
    {                                                                          \
        v2h m2 = xl2 + xr2;                                                    \
        m2 += we0 * h2bits(e00);                                               \
        m2 += we1 * h2bits(e11);                                               \
        m2 += we2 * h2bits(e22);                                               \
        v2h lk = m2 * vk02;                                                    \
        m2 = __builtin_elementwise_max(m2, lk);                                \
        float p;                                                               \
        p = __builtin_amdgcn_fdot2(m2, at2, 0.0f, false);                      \
        p += dpp_swap<0xB1>(p);                                                \
        p += dpp_swap<0x4E>(p);                                                \
        p += dpp_swap<0x141>(p);                                               \
        float ex = exp2f(p);                                                   \
        d_  += ex;                                                             \
        a0_ = fmaf(ex, (float)xl2.x, a0_);                                     \
        a1_ = fmaf(ex, (float)xl2.y, a1_);                                     \
    }

    int j = beg;
    for (; j + 7 < end; j += 8) {
        uint2 q[8];
        v2h   xl[8];
        int      s[8];
        unsigned e00[8], e11[8], e22[8];
#pragma unroll
        for (int i = 0; i < 8; i++) q[i] = csr2[j + i];
#pragma unroll
        for (int i = 0; i < 8; i++) {
            DECODE(q[i], s[i], e00[i], e11[i], e22[i]);
            xl[i] = *(const v2h*)&XL[((size_t)s[i] << 7) + c0];
        }
#pragma unroll
        for (int i = 0; i < 8; i++)
            EDGE_STEP(e00[i], e11[i], e22[i], xl[i], dacc[i], a0[i], a1[i]);
    }
    if (j + 3 < end) {
        uint2 q[4];
        v2h   xl[4];
        int      s[4];
        unsigned e00[4], e11[4], e22[4];
#pragma unroll
        for (int i = 0; i < 4; i++) q[i] = csr2[j + i];
#pragma unroll
        for (int i = 0; i < 4; i++) {
            DECODE(q[i], s[i], e00[i], e11[i], e22[i]);
            xl[i] = *(const v2h*)&XL[((size_t)s[i] << 7) + c0];
        }
#pragma unroll
        for (int i = 0; i < 4; i++)
            EDGE_STEP(e00[i], e11[i], e22[i], xl[i], dacc[i], a0[i], a1[i]);
        j += 4;
    }
    for (; j < end; j++) {
        uint2 q = csr2[j];
        int s; unsigned e00, e11, e22;
        DECODE(q, s, e00, e11, e22);
        v2h xl = *(const v2h*)&XL[((size_t)s << 7) + c0];
        EDGE_STEP(e00, e11, e22, xl, dacc[0], a0[0], a1[0]);
    }

    // self loop: mean of incoming attrs (0 if no in-edges), xl = own row
    {
        int c = end - beg;
        float inv = (c > 0) ? (1.0f / (float)c) : 0.0f;
        unsigned e00 = hbits(as0 * inv) * 0x10001u;
        unsigned e11 = hbits(as1 * inv) * 0x10001u;
        unsigned e22 = hbits(as2 * inv) * 0x10001u;
        v2h xl = *(const v2h*)&XL[(size_t)n * HC + c0];
        EDGE_STEP(e00, e11, e22, xl, dacc[0], a0[0], a1[0]);
    }
#undef EDGE_STEP
#undef DECODE

    float den  = ((dacc[0] + dacc[1]) + (dacc[2] + dacc[3])) +
                 ((dacc[4] + dacc[5]) + (dacc[6] + dacc[7]));
    float acc0 = ((a0[0] + a0[1]) + (a0[2] + a0[3])) +
                 ((a0[4] + a0[5]) + (a0[6] + a0[7]));
    float acc1 = ((a1[0] + a1[1]) + (a1[2] + a1[3])) +
                 ((a1[4] + a1[5]) + (a1[6] + a1[7]));

    float inv = 1.0f / (den + 1e-16f);
    float o0 = acc0 * inv + bias[c0];
    float o1 = acc1 * inv + bias[c0 + 1];
    o0 = (o0 > 0.f) ? o0 : expm1f(o0);   // ELU (both layers)
    o1 = (o1 > 0.f) ? o1 : expm1f(o1);

    if (!FUSE) {
        __half2 hv = __floats2half2_rn(o0, o1);
        *(__half2*)&OUT[(size_t)n * HC + c0] = hv;
    } else {
        // wave-local final linear: no barrier (same-wave LDS write->read)
        hrow[w * HC + c0]     = o0;
        hrow[w * HC + c0 + 1] = o1;
        int o = lane & 31, half = lane >> 5;
        const float* hr = &hrow[w * HC + half * 64];
        const float* wr = &wf_s[o * 132 + half * 64];
        float acc = 0.f;
#pragma unroll
        for (int c = 0; c < 64; c += 4) {
            float4 hv = *(const float4*)&hr[c];
            float4 wv = *(const float4*)&wr[c];
            acc = fmaf(hv.x, wv.x, acc);
            acc = fmaf(hv.y, wv.y, acc);
            acc = fmaf(hv.z, wv.z, acc);
            acc = fmaf(hv.w, wv.w, acc);
        }
        acc += __shfl_xor(acc, 32);
        if (lane < 32) out2[(size_t)n * OUTC + o] = acc + bf[o];
    }
}

// ---------------------------------------------------------------------------
extern "C" void kernel_launch(void* const* d_in, const int* in_sizes, int n_in,
                              void* d_out, int out_size, void* d_ws, size_t ws_size,
                              hipStream_t stream)
{
    const float* x     = (const float*)d_in[0];
    const int*   esrc  = (const int*)d_in[1];
    const int*   edst  = (const int*)d_in[2];
    const float* eattr = (const float*)d_in[3];
    const float* Wl1 = (const float*)d_in[4];  const float* bl1 = (const float*)d_in[5];
    const float* Wr1 = (const float*)d_in[6];  const float* br1 = (const float*)d_in[7];
    const float* We1 = (const float*)d_in[8];  const float* att1 = (const float*)d_in[9];
    const float* b1  = (const float*)d_in[10];
    const float* Wl2 = (const float*)d_in[11]; const float* bl2 = (const float*)d_in[12];
    const float* Wr2 = (const float*)d_in[13]; const float* br2 = (const float*)d_in[14];
    const float* We2 = (const float*)d_in[15]; const float* att2 = (const float*)d_in[16];
    const float* b2  = (const float*)d_in[17];
    const float* Wf  = (const float*)d_in[18]; const float* bf  = (const float*)d_in[19];

    char* ws = (char*)d_ws;
    size_t off = 0;
    auto alloc = [&](size_t bytes) -> void* {
        void* p = ws + off;
        off += (bytes + 255) & ~(size_t)255;
        return p;
    };
    int*    cnt      = (int*)alloc((size_t)NNODES * 4);
    int*    offsets  = (int*)alloc((size_t)(NNODES + 1) * 4);
    int*    slot     = (int*)alloc((size_t)NEDGES * 4);
    uint2*  csr2     = (uint2*)alloc((size_t)NEDGES * 8);
    int*    blocksum = (int*)alloc((size_t)NBLK * 4);
    __half* x16      = (__half*)alloc((size_t)NNODES * 64 * 2);
    __half* WH1      = (__half*)alloc((size_t)256 * 64 * 2);
    __half* WH2      = (__half*)alloc((size_t)256 * 128 * 2);
    __half* XL       = (__half*)alloc((size_t)NNODES * HC * 2);
    __half* XR       = (__half*)alloc((size_t)NNODES * HC * 2);
    __half* H1       = (__half*)alloc((size_t)NNODES * HC * 2);

    hipMemsetAsync(cnt, 0, (size_t)NNODES * 4, stream);

    count_convert_kernel<<<CB + (CONV + 255) / 256, 256, 0, stream>>>(
        edst, cnt, slot, x, Wl1, Wr1, Wl2, Wr2, x16, WH1, WH2);
    scan1_kernel<<<NBLK, 256, 0, stream>>>(cnt, offsets, blocksum);
    scan2_kernel<<<1, 256, 0, stream>>>(blocksum);
    scan3_kernel<<<NBLK, 256, 0, stream>>>(offsets, blocksum);

    // place (real edges, 8B records) + layer-1 transform, fused
    place_transform_kernel<<<CB + NNODES / 32, 256, 0, stream>>>(
        esrc, edst, eattr, offsets, slot, csr2,
        x16, WH1, bl1, br1, XL, XR);

    // layer 1 aggregation (self loop folded in)
    agg_kernel<0><<<NNODES / 4, 256, 0, stream>>>(XL, XR, csr2, offsets,
                                                  We1, att1, b1, H1, nullptr, nullptr, nullptr);
    // layer 2 (+ fused final linear, wave-local)
    transform_mfma_kernel<128><<<NNODES / 32, 256, 0, stream>>>(H1, WH2, bl2, br2, XL, XR);
    agg_kernel<1><<<NNODES / 4, 256, 0, stream>>>(XL, XR, csr2, offsets,
                                                  We2, att2, b2, nullptr, Wf, bf, (float*)d_out);
}